// Round 7
// baseline (822.911 us; speedup 1.0000x reference)
//
#include <hip/hip_runtime.h>
#include <hip/hip_bf16.h>

// B=8, O=1024, Q=2048, QD=1024, SG=1200  (SG padded to 1216 for K%32==0)
//   GEMM1: query = query_in @ W^T        f16-split 3-term, 128² 8-phase 3-slot, out hi/lo f16
//   GEMM2: scores = query @ ctx^T        f16-split 3-term, 256² 8-wave 4-slot pipeline
//   softmax rows of 2048 (in-place in d_out) + f16 copy of weights
//   GEMM3: mix = weights @ ctx           pure f16 NT via pre-transposed ctxT, 128² 8-phase 3-slot

typedef _Float16 half8 __attribute__((ext_vector_type(8)));
typedef _Float16 half4v __attribute__((ext_vector_type(4)));
typedef float    f32x4 __attribute__((ext_vector_type(4)));

#define AS1C(p) ((const __attribute__((address_space(1))) void*)(p))
#define AS3(p)  ((__attribute__((address_space(3))) void*)(p))

#define WAITV8() do { asm volatile("s_waitcnt vmcnt(8)" ::: "memory"); __builtin_amdgcn_sched_barrier(0); } while(0)
#define WAITV4() do { asm volatile("s_waitcnt vmcnt(4)" ::: "memory"); __builtin_amdgcn_sched_barrier(0); } while(0)
#define WAITV0() do { asm volatile("s_waitcnt vmcnt(0)" ::: "memory"); __builtin_amdgcn_sched_barrier(0); } while(0)
#define WAITL0() do { asm volatile("s_waitcnt lgkmcnt(0)" ::: "memory"); __builtin_amdgcn_sched_barrier(0); } while(0)

// ======================= staging helpers =======================
// LDS dest linear (global_load_lds requirement); conflict-free ds_read via
// pre-swizzled GLOBAL source: chunk koff of row r lands at slot koff^((r>>1)&3).

// 128 rows x 32 f16 (8 KB), 256 threads, 2 loads/thread
__device__ __forceinline__ void stage_tile(const _Float16* __restrict__ X, _Float16* s,
                                           int t, long row0, long rowmax, int ld, int k0)
{
#pragma unroll
    for (int j = 0; j < 2; ++j) {
        const int L = t + 256 * j;
        const int r = L >> 2;
        const int slot = L & 3;
        const int koff = slot ^ ((r >> 1) & 3);
        long grow = row0 + r; if (grow > rowmax) grow = rowmax;
        const _Float16* src = X + grow * (long)ld + k0 + koff * 8;
        _Float16* dst = s + (long)((t & ~63) + 256 * j) * 8;
        __builtin_amdgcn_global_load_lds(AS1C(src), AS3(dst), 16, 0, 0);
    }
}

// 256 rows x 32 f16 (16 KB), 512 threads, 2 loads/thread, no row guard (exact dims)
__device__ __forceinline__ void stage256(const _Float16* __restrict__ X, _Float16* s,
                                         int t, long row0, int ld, int k0)
{
#pragma unroll
    for (int j = 0; j < 2; ++j) {
        const int L = t + 512 * j;
        const int r = L >> 2;
        const int slot = L & 3;
        const int koff = slot ^ ((r >> 1) & 3);
        const _Float16* src = X + (row0 + r) * (long)ld + k0 + koff * 8;
        _Float16* dst = s + (long)((t & ~63) + 512 * j) * 8;
        __builtin_amdgcn_global_load_lds(AS1C(src), AS3(dst), 16, 0, 0);
    }
}

// swizzled fragment read: 8 f16 along K for (local row, k-chunk kslot)
__device__ __forceinline__ half8 frag(const _Float16* s, int row, int kslot)
{
    return *(const half8*)(s + row * 32 + ((kslot ^ ((row >> 1) & 3)) << 3));
}

// ======================= GEMM2: 256x256 8-wave 4-slot pipeline (unchanged, R6-proven) =======================
#define T2K 38   // 1216/32
__global__ __launch_bounds__(512, 2) void gemm2_8p(
    const _Float16* __restrict__ Ahp, const _Float16* __restrict__ Alp,
    const _Float16* __restrict__ Bhp, const _Float16* __restrict__ Blp,
    float* __restrict__ Cf)
{
    const int t = threadIdx.x;
    const int bz = blockIdx.z;
    const _Float16* A_h = Ahp + bz * (1024L * 1216);
    const _Float16* A_l = Alp + bz * (1024L * 1216);
    const _Float16* B_h = Bhp + bz * (2048L * 1216);
    const _Float16* B_l = Blp + bz * (2048L * 1216);

    __shared__ __align__(16) _Float16 slots[4][2][256 * 32];   // 128 KiB

    const long row0 = (long)blockIdx.y * 256;
    const long col0 = (long)blockIdx.x * 256;

    const int wid = t >> 6, lane = t & 63;
    const int wr = wid >> 2, wc = wid & 3;
    const int fr = lane & 15, kslot = lane >> 4;

    f32x4 acc[8][4];
#pragma unroll
    for (int i = 0; i < 8; ++i)
#pragma unroll
        for (int j = 0; j < 4; ++j) acc[i][j] = (f32x4){0.f, 0.f, 0.f, 0.f};

    stage256(A_h, &slots[0][0][0], t, row0, 1216, 0);
    stage256(B_h, &slots[0][1][0], t, col0, 1216, 0);
    stage256(A_l, &slots[1][0][0], t, row0, 1216, 0);
    stage256(B_l, &slots[1][1][0], t, col0, 1216, 0);
    stage256(A_h, &slots[2][0][0], t, row0, 1216, 32);
    stage256(B_h, &slots[2][1][0], t, col0, 1216, 32);

    for (int tt = 0; tt < T2K; ++tt) {
        const int s0 = (2 * tt) & 3, s1 = (2 * tt + 1) & 3;

        if (tt < T2K - 1) WAITV8(); else WAITV4();
        __builtin_amdgcn_s_barrier();

        half8 a_h[8], b_h[4];
#pragma unroll
        for (int i = 0; i < 8; ++i) a_h[i] = frag(&slots[s0][0][0], wr * 128 + i * 16 + fr, kslot);
#pragma unroll
        for (int i = 0; i < 4; ++i) b_h[i] = frag(&slots[s0][1][0], wc * 64 + i * 16 + fr, kslot);

        if (tt < T2K - 1) {
            const int k0 = (tt + 1) * 32, sl = (2 * tt + 3) & 3;
            stage256(A_l, &slots[sl][0][0], t, row0, 1216, k0);
            stage256(B_l, &slots[sl][1][0], t, col0, 1216, k0);
        }
        __builtin_amdgcn_s_barrier();
        WAITL0();
        __builtin_amdgcn_s_setprio(1);
#pragma unroll
        for (int mi = 0; mi < 8; ++mi)
#pragma unroll
            for (int ni = 0; ni < 4; ++ni)
                acc[mi][ni] = __builtin_amdgcn_mfma_f32_16x16x32_f16(a_h[mi], b_h[ni], acc[mi][ni], 0, 0, 0);
        __builtin_amdgcn_s_setprio(0);

        if (tt < T2K - 1) WAITV8(); else WAITV0();
        __builtin_amdgcn_s_barrier();

        half8 a_l[8], b_l[4];
#pragma unroll
        for (int i = 0; i < 8; ++i) a_l[i] = frag(&slots[s1][0][0], wr * 128 + i * 16 + fr, kslot);
#pragma unroll
        for (int i = 0; i < 4; ++i) b_l[i] = frag(&slots[s1][1][0], wc * 64 + i * 16 + fr, kslot);

        if (tt < T2K - 2) {
            const int k0 = (tt + 2) * 32, sl = (2 * tt + 4) & 3;
            stage256(A_h, &slots[sl][0][0], t, row0, 1216, k0);
            stage256(B_h, &slots[sl][1][0], t, col0, 1216, k0);
        }
        __builtin_amdgcn_s_barrier();
        WAITL0();
        __builtin_amdgcn_s_setprio(1);
#pragma unroll
        for (int mi = 0; mi < 8; ++mi)
#pragma unroll
            for (int ni = 0; ni < 4; ++ni) {
                acc[mi][ni] = __builtin_amdgcn_mfma_f32_16x16x32_f16(a_h[mi], b_l[ni], acc[mi][ni], 0, 0, 0);
                acc[mi][ni] = __builtin_amdgcn_mfma_f32_16x16x32_f16(a_l[mi], b_h[ni], acc[mi][ni], 0, 0, 0);
            }
        __builtin_amdgcn_s_setprio(0);
    }

    const int r4 = (lane >> 4) * 4;
    float* C = Cf + bz * (1024L * 2048);
#pragma unroll
    for (int mi = 0; mi < 8; ++mi)
#pragma unroll
        for (int ni = 0; ni < 4; ++ni) {
            const long colg = col0 + wc * 64 + ni * 16 + fr;
#pragma unroll
            for (int r = 0; r < 4; ++r) {
                const long rowg = row0 + wr * 128 + mi * 16 + r4 + r;
                C[rowg * 2048 + colg] = acc[mi][ni][r];
            }
        }
}

// ======================= GEMM1/GEMM3: 128x128 8-phase 3-slot pipeline =======================
// 256 threads, 4 waves (2x2), per-wave 64x64. LDS 3 slots x 16KB = 48KB -> 3 blocks/CU.
// Halves: SPLIT ? {hi(t0),lo(t0),hi(t1),...} : {t0,t1,...}; slot(g)=g%3, depth-2 in flight.
// Race-free slot reuse: ds_read -> lgkmcnt(0) -> barrier (all reads retired) -> overwrite.
template<bool SPLIT, bool OUT16>
__global__ __launch_bounds__(256, 3) void gemm8p(
    const _Float16* __restrict__ Ah, const _Float16* __restrict__ Al,
    const _Float16* __restrict__ Bh, const _Float16* __restrict__ Bl,
    float* __restrict__ Cf, _Float16* __restrict__ Ch, _Float16* __restrict__ Cl,
    int N, int K, int lda, int ldb, int ldc,
    long sA, long sB, long sC)
{
    const int t = threadIdx.x;
    const int bz = blockIdx.z;
    const _Float16* A_h = Ah + bz * sA;
    const _Float16* B_h = Bh + bz * sB;
    const _Float16* A_l = SPLIT ? (Al + bz * sA) : nullptr;
    const _Float16* B_l = SPLIT ? (Bl + bz * sB) : nullptr;

    __shared__ __align__(16) _Float16 slots[3][2][128 * 32];   // 48 KiB

    const long row0 = (long)blockIdx.y * 128;
    const long col0 = (long)blockIdx.x * 128;
    const long rowAmax = row0 + 127;           // M dims are exact multiples of 128
    const long rowBmax = N - 1;

    const int wid = t >> 6, lane = t & 63;
    const int wm = (wid >> 1) * 64, wn = (wid & 1) * 64;
    const int fr = lane & 15, kslot = lane >> 4;

    f32x4 acc[4][4];
#pragma unroll
    for (int i = 0; i < 4; ++i)
#pragma unroll
        for (int j = 0; j < 4; ++j) acc[i][j] = (f32x4){0.f, 0.f, 0.f, 0.f};

    const int KT = K >> 5;
    const int G = SPLIT ? (KT << 1) : KT;

    // prologue: stage halves 0,1,2 into slots 0,1,2
#pragma unroll
    for (int h = 0; h < 3; ++h) {
        const int tn = SPLIT ? (h >> 1) : h;
        const bool hi = SPLIT ? !(h & 1) : true;
        stage_tile(hi ? A_h : A_l, &slots[h][0][0], t, row0, rowAmax, lda, tn * 32);
        stage_tile(hi ? B_h : B_l, &slots[h][1][0], t, col0, rowBmax, ldb, tn * 32);
    }

    half8 a_hi[4], b_hi[4];
    int sl = 0;
    for (int g = 0; g < G; ++g) {
        const int rem = G - 1 - g;
        if (rem >= 2) WAITV8(); else if (rem == 1) WAITV4(); else WAITV0();
        __builtin_amdgcn_s_barrier();          // half g resident for all waves

        half8 a[4], b[4];
#pragma unroll
        for (int i = 0; i < 4; ++i) {
            a[i] = frag(&slots[sl][0][0], wm + i * 16 + fr, kslot);
            b[i] = frag(&slots[sl][1][0], wn + i * 16 + fr, kslot);
        }
        WAITL0();                               // my reads retired
        __builtin_amdgcn_s_barrier();          // ALL waves' reads retired -> slot free

        if (g + 3 < G) {                        // overwrite slot sl with half g+3
            const int gn = g + 3;
            const int tn = SPLIT ? (gn >> 1) : gn;
            const bool hi = SPLIT ? !(gn & 1) : true;
            stage_tile(hi ? A_h : A_l, &slots[sl][0][0], t, row0, rowAmax, lda, tn * 32);
            stage_tile(hi ? B_h : B_l, &slots[sl][1][0], t, col0, rowBmax, ldb, tn * 32);
        }

        __builtin_amdgcn_s_setprio(1);
        if (!SPLIT || !(g & 1)) {
            // hi phase: acc += a_hi*b_hi; keep hi frags for the lo phase
#pragma unroll
            for (int mi = 0; mi < 4; ++mi)
#pragma unroll
                for (int ni = 0; ni < 4; ++ni)
                    acc[mi][ni] = __builtin_amdgcn_mfma_f32_16x16x32_f16(a[mi], b[ni], acc[mi][ni], 0, 0, 0);
            if (SPLIT) {
#pragma unroll
                for (int i = 0; i < 4; ++i) { a_hi[i] = a[i]; b_hi[i] = b[i]; }
            }
        } else {
            // lo phase: acc += a_hi*b_lo + a_lo*b_hi
#pragma unroll
            for (int mi = 0; mi < 4; ++mi)
#pragma unroll
                for (int ni = 0; ni < 4; ++ni) {
                    acc[mi][ni] = __builtin_amdgcn_mfma_f32_16x16x32_f16(a_hi[mi], b[ni], acc[mi][ni], 0, 0, 0);
                    acc[mi][ni] = __builtin_amdgcn_mfma_f32_16x16x32_f16(a[mi], b_hi[ni], acc[mi][ni], 0, 0, 0);
                }
        }
        __builtin_amdgcn_s_setprio(0);

        sl = (sl == 2) ? 0 : sl + 1;
    }

    // C/D layout (m89-verified): col = lane&15, row = (lane>>4)*4 + reg
    const int r4 = (lane >> 4) * 4;
    float* C_f = OUT16 ? nullptr : (Cf + bz * sC);
#pragma unroll
    for (int mi = 0; mi < 4; ++mi)
#pragma unroll
        for (int ni = 0; ni < 4; ++ni) {
            const int colg = (int)col0 + wn + ni * 16 + fr;
#pragma unroll
            for (int r = 0; r < 4; ++r) {
                const long rowg = row0 + wm + mi * 16 + r4 + r;
                const float v = acc[mi][ni][r];
                if (OUT16) {
                    if (colg < ldc) {                 // ldc = padded width (zeros in pad)
                        const float vv = (colg < N) ? v : 0.f;
                        const _Float16 hi = (_Float16)vv;
                        const _Float16 lo = (_Float16)(vv - (float)hi);
                        Ch[rowg * ldc + colg] = hi;
                        Cl[rowg * ldc + colg] = lo;
                    }
                } else {
                    if (colg < N) C_f[rowg * (long)ldc + colg] = v;
                }
            }
        }
}

// fused fp32 -> (hi,lo) f16 split for query_in and W
__global__ __launch_bounds__(256) void qw_cvt(
    const float* __restrict__ Q, _Float16* __restrict__ QH, _Float16* __restrict__ QL,
    const float* __restrict__ Wt, _Float16* __restrict__ WH, _Float16* __restrict__ WL)
{
    const long NQ = 8192L * 1024 / 4;
    const long NT = NQ + 1200L * 1024 / 4;
    for (long i = (long)blockIdx.x * 256 + threadIdx.x; i < NT; i += (long)gridDim.x * 256) {
        const float* src; _Float16 *dh, *dl; long j;
        if (i < NQ) { j = i; src = Q; dh = QH; dl = QL; }
        else        { j = i - NQ; src = Wt; dh = WH; dl = WL; }
        float4 v = *(const float4*)(src + j * 4);
        const _Float16 h0 = (_Float16)v.x, h1 = (_Float16)v.y, h2 = (_Float16)v.z, h3 = (_Float16)v.w;
        const _Float16 l0 = (_Float16)(v.x - (float)h0), l1 = (_Float16)(v.y - (float)h1);
        const _Float16 l2 = (_Float16)(v.z - (float)h2), l3 = (_Float16)(v.w - (float)h3);
        *(half4v*)(dh + j * 4) = (half4v){h0, h1, h2, h3};
        *(half4v*)(dl + j * 4) = (half4v){l0, l1, l2, l3};
    }
}

// fused ctx prep: one read of ctx f32 -> hi/lo split [8][2048][1216] + f16 transpose [8][1200][2048]
__global__ __launch_bounds__(256) void ctx_prep(const float* __restrict__ X,
    _Float16* __restrict__ H, _Float16* __restrict__ L, _Float16* __restrict__ T)
{
    const int b = blockIdx.z;
    const float* Xb = X + (long)b * 2048 * 1200;
    _Float16* Hb = H + (long)b * 2048 * 1216;
    _Float16* Lb = L + (long)b * 2048 * 1216;
    _Float16* Tb = T + (long)b * 1200 * 2048;
    __shared__ _Float16 tl[32][33];
    const int tx = threadIdx.x & 31, ty = threadIdx.x >> 5;
    const int s0 = blockIdx.x * 32, q0 = blockIdx.y * 32;
#pragma unroll
    for (int p = 0; p < 4; ++p) {
        const int q = q0 + ty + p * 8, s = s0 + tx;
        const float v = (s < 1200) ? Xb[(long)q * 1200 + s] : 0.f;
        const _Float16 hi = (_Float16)v;
        Hb[(long)q * 1216 + s] = hi;
        Lb[(long)q * 1216 + s] = (_Float16)(v - (float)hi);
        tl[tx][ty + p * 8] = hi;
    }
    __syncthreads();
#pragma unroll
    for (int p = 0; p < 4; ++p) {
        const int s = s0 + ty + p * 8;
        if (s < 1200) Tb[(long)s * 2048 + q0 + tx] = tl[ty + p * 8][tx];
    }
}

// in-place row softmax (2048) + f16 copy for GEMM3
__global__ __launch_bounds__(256) void softmax_k(float* __restrict__ w, _Float16* __restrict__ w16)
{
    float* p = w + (long)blockIdx.x * 2048;
    half4v* p16 = (half4v*)(w16 + (long)blockIdx.x * 2048);
    const int t = threadIdx.x;
    float4 v0 = ((const float4*)p)[t];
    float4 v1 = ((const float4*)p)[t + 256];

    float m = fmaxf(fmaxf(fmaxf(v0.x, v0.y), fmaxf(v0.z, v0.w)),
                    fmaxf(fmaxf(v1.x, v1.y), fmaxf(v1.z, v1.w)));
#pragma unroll
    for (int off = 1; off < 64; off <<= 1) m = fmaxf(m, __shfl_xor(m, off));
    __shared__ float redm[4], reds[4];
    const int wave = t >> 6, lane = t & 63;
    if (lane == 0) redm[wave] = m;
    __syncthreads();
    m = fmaxf(fmaxf(redm[0], redm[1]), fmaxf(redm[2], redm[3]));

    float e[8];
    e[0] = __expf(v0.x - m); e[1] = __expf(v0.y - m);
    e[2] = __expf(v0.z - m); e[3] = __expf(v0.w - m);
    e[4] = __expf(v1.x - m); e[5] = __expf(v1.y - m);
    e[6] = __expf(v1.z - m); e[7] = __expf(v1.w - m);

    float s = ((e[0] + e[1]) + (e[2] + e[3])) + ((e[4] + e[5]) + (e[6] + e[7]));
#pragma unroll
    for (int off = 1; off < 64; off <<= 1) s += __shfl_xor(s, off);
    if (lane == 0) reds[wave] = s;
    __syncthreads();
    s = (reds[0] + reds[1]) + (reds[2] + reds[3]);

    const float inv = 1.0f / s;
    float o0 = e[0] * inv, o1 = e[1] * inv, o2 = e[2] * inv, o3 = e[3] * inv;
    float o4 = e[4] * inv, o5 = e[5] * inv, o6 = e[6] * inv, o7 = e[7] * inv;
    ((float4*)p)[t]       = make_float4(o0, o1, o2, o3);
    ((float4*)p)[t + 256] = make_float4(o4, o5, o6, o7);
    p16[t]       = (half4v){(_Float16)o0, (_Float16)o1, (_Float16)o2, (_Float16)o3};
    p16[t + 256] = (half4v){(_Float16)o4, (_Float16)o5, (_Float16)o6, (_Float16)o7};
}

extern "C" void kernel_launch(void* const* d_in, const int* in_sizes, int n_in,
                              void* d_out, int out_size, void* d_ws, size_t ws_size,
                              hipStream_t stream)
{
    const float* query_in = (const float*)d_in[0]; // [8,1024,1024]
    const float* context  = (const float*)d_in[1]; // [8,2048,1200]
    const float* W        = (const float*)d_in[2]; // [1200,1024]

    float* mix    = (float*)d_out;                 // [8,1024,1200]
    float* scores = (float*)d_out + 9830400LL;     // [8,1024,2048] -> softmax in place

    // ws layout (halfs); ~220 MB
    _Float16* qh  = (_Float16*)d_ws;               // query_in hi  [8192,1024]
    _Float16* ql  = qh  + 8388608;                 // query_in lo
    _Float16* wh  = ql  + 8388608;                 // W hi         [1200,1024]
    _Float16* wl  = wh  + 1228800;                 // W lo
    _Float16* ch  = wl  + 1228800;                 // ctx hi       [16384,1216] (zero-pad 1200..1215)
    _Float16* cl  = ch  + 19922944;                // ctx lo
    _Float16* ct  = cl  + 19922944;                // ctxT f16     [8][1200][2048]
    _Float16* qeh = ct  + 19660800;                // query hi     [8192,1216]
    _Float16* qel = qeh + 9961472;                 // query lo
    _Float16* w16 = qel + 9961472;                 // weights f16  [8192,2048]

    dim3 blk(256);

    qw_cvt<<<2400, blk, 0, stream>>>(query_in, qh, ql, W, wh, wl);
    ctx_prep<<<dim3(38, 64, 8), blk, 0, stream>>>(context, ch, cl, ct);

    // GEMM1: query(hi/lo)[8192,1216] = qin[8192,1024] @ W[1200,1024]^T  (split, out f16 pair)
    gemm8p<true, true><<<dim3(10, 64, 1), blk, 0, stream>>>(
        qh, ql, wh, wl, nullptr, qeh, qel,
        1200, 1024, 1024, 1024, 1216, 0, 0, 0);

    // GEMM2: scores[b][1024,2048] = qe_b[1024,1216] @ ctx_b[2048,1216]^T  (split, 8-wave pipeline)
    gemm2_8p<<<dim3(8, 4, 8), dim3(512), 0, stream>>>(qeh, qel, ch, cl, scores);

    softmax_k<<<dim3(8192), blk, 0, stream>>>(scores, w16);

    // GEMM3: mix[b][1024,1200] = w16_b[1024,2048] @ ctxT_b[1200,2048]^T  (pure f16, out f32)
    gemm8p<false, false><<<dim3(10, 8, 8), blk, 0, stream>>>(
        w16, nullptr, ct, nullptr, mix, nullptr, nullptr,
        1200, 2048, 2048, 2048, 1200, 1024L * 2048, 1200L * 2048, 1024L * 1200);
}

// Round 10
// 501.301 us; speedup vs baseline: 1.6415x; 1.6415x over previous
//
#include <hip/hip_runtime.h>
#include <hip/hip_bf16.h>

// B=8, O=1024, Q=2048, QD=1024, SG=1200  (SG padded to 1216 for K%32==0)
//   GEMM1: query = query_in @ W^T        f16-split 3-term, 128² 2-phase, XCD-swizzled (M-stripe/XCD)
//   GEMM2: scores = query @ ctx^T        f16-split 3-term, 256² 8-wave 4-slot pipeline, batch/XCD
//   softmax rows of 2048 (in-place in d_out) + f16 copy of weights
//   GEMM3: mix = weights @ ctx           pure f16 NT via pre-transposed ctxT, 128² 2-phase, batch/XCD
// R7 lesson: GEMM1/3 are L2-locality-bound (FETCH 777MB vs 72MB ideal at default
// round-robin block->XCD). Swizzle co-locates panel sharers on one XCD L2.

typedef _Float16 half8 __attribute__((ext_vector_type(8)));
typedef _Float16 half4v __attribute__((ext_vector_type(4)));
typedef float    f32x4 __attribute__((ext_vector_type(4)));

#define AS1C(p) ((const __attribute__((address_space(1))) void*)(p))
#define AS3(p)  ((__attribute__((address_space(3))) void*)(p))

#define WAITV8() do { asm volatile("s_waitcnt vmcnt(8)" ::: "memory"); __builtin_amdgcn_sched_barrier(0); } while(0)
#define WAITV4() do { asm volatile("s_waitcnt vmcnt(4)" ::: "memory"); __builtin_amdgcn_sched_barrier(0); } while(0)
#define WAITV0() do { asm volatile("s_waitcnt vmcnt(0)" ::: "memory"); __builtin_amdgcn_sched_barrier(0); } while(0)
#define WAITL0() do { asm volatile("s_waitcnt lgkmcnt(0)" ::: "memory"); __builtin_amdgcn_sched_barrier(0); } while(0)

// ======================= staging helpers =======================
// LDS dest linear (global_load_lds requirement); conflict-free ds_read via
// pre-swizzled GLOBAL source: chunk koff of row r lands at slot koff^((r>>1)&3).

// 128 rows x 32 f16 (8 KB), 256 threads
__device__ __forceinline__ void stage_tile(const _Float16* __restrict__ X, _Float16* s,
                                           int t, long row0, long rowmax, int ld, int k0)
{
#pragma unroll
    for (int j = 0; j < 2; ++j) {
        const int L = t + 256 * j;
        const int r = L >> 2;
        const int slot = L & 3;
        const int koff = slot ^ ((r >> 1) & 3);
        long grow = row0 + r; if (grow > rowmax) grow = rowmax;
        const _Float16* src = X + grow * (long)ld + k0 + koff * 8;
        _Float16* dst = s + (long)((t & ~63) + 256 * j) * 8;
        __builtin_amdgcn_global_load_lds(AS1C(src), AS3(dst), 16, 0, 0);
    }
}

// 256 rows x 32 f16 (16 KB), 512 threads, no row guard (exact dims)
__device__ __forceinline__ void stage256(const _Float16* __restrict__ X, _Float16* s,
                                         int t, long row0, int ld, int k0)
{
#pragma unroll
    for (int j = 0; j < 2; ++j) {
        const int L = t + 512 * j;
        const int r = L >> 2;
        const int slot = L & 3;
        const int koff = slot ^ ((r >> 1) & 3);
        const _Float16* src = X + (row0 + r) * (long)ld + k0 + koff * 8;
        _Float16* dst = s + (long)((t & ~63) + 512 * j) * 8;
        __builtin_amdgcn_global_load_lds(AS1C(src), AS3(dst), 16, 0, 0);
    }
}

// swizzled fragment read: 8 f16 along K for (local row, k-chunk kslot)
__device__ __forceinline__ half8 frag(const _Float16* s, int row, int kslot)
{
    return *(const half8*)(s + row * 32 + ((kslot ^ ((row >> 1) & 3)) << 3));
}

// ======================= GEMM2: 256x256 8-wave 4-slot pipeline (R6-proven) =======================
// Flat grid 256; batch pinned to XCD: bz = bid&7 (bid%8 == XCD round-robin assumption, m09/m157).
#define T2K 38   // 1216/32
__global__ __launch_bounds__(512, 2) void gemm2_8p(
    const _Float16* __restrict__ Ahp, const _Float16* __restrict__ Alp,
    const _Float16* __restrict__ Bhp, const _Float16* __restrict__ Blp,
    float* __restrict__ Cf)
{
    const int t = threadIdx.x;
    const int bid = blockIdx.x;
    const int bz = bid & 7;           // batch -> XCD
    const int rr = bid >> 3;          // 0..31 within batch
    const int by = rr >> 3;           // 0..3 (M)
    const int bx = rr & 7;            // 0..7 (N)

    const _Float16* A_h = Ahp + bz * (1024L * 1216);
    const _Float16* A_l = Alp + bz * (1024L * 1216);
    const _Float16* B_h = Bhp + bz * (2048L * 1216);
    const _Float16* B_l = Blp + bz * (2048L * 1216);

    __shared__ __align__(16) _Float16 slots[4][2][256 * 32];   // 128 KiB

    const long row0 = (long)by * 256;
    const long col0 = (long)bx * 256;

    const int wid = t >> 6, lane = t & 63;
    const int wr = wid >> 2, wc = wid & 3;
    const int fr = lane & 15, kslot = lane >> 4;

    f32x4 acc[8][4];
#pragma unroll
    for (int i = 0; i < 8; ++i)
#pragma unroll
        for (int j = 0; j < 4; ++j) acc[i][j] = (f32x4){0.f, 0.f, 0.f, 0.f};

    stage256(A_h, &slots[0][0][0], t, row0, 1216, 0);
    stage256(B_h, &slots[0][1][0], t, col0, 1216, 0);
    stage256(A_l, &slots[1][0][0], t, row0, 1216, 0);
    stage256(B_l, &slots[1][1][0], t, col0, 1216, 0);
    stage256(A_h, &slots[2][0][0], t, row0, 1216, 32);
    stage256(B_h, &slots[2][1][0], t, col0, 1216, 32);

    for (int tt = 0; tt < T2K; ++tt) {
        const int s0 = (2 * tt) & 3, s1 = (2 * tt + 1) & 3;

        if (tt < T2K - 1) WAITV8(); else WAITV4();
        __builtin_amdgcn_s_barrier();

        half8 a_h[8], b_h[4];
#pragma unroll
        for (int i = 0; i < 8; ++i) a_h[i] = frag(&slots[s0][0][0], wr * 128 + i * 16 + fr, kslot);
#pragma unroll
        for (int i = 0; i < 4; ++i) b_h[i] = frag(&slots[s0][1][0], wc * 64 + i * 16 + fr, kslot);

        if (tt < T2K - 1) {
            const int k0 = (tt + 1) * 32, sl = (2 * tt + 3) & 3;
            stage256(A_l, &slots[sl][0][0], t, row0, 1216, k0);
            stage256(B_l, &slots[sl][1][0], t, col0, 1216, k0);
        }
        __builtin_amdgcn_s_barrier();
        WAITL0();
        __builtin_amdgcn_s_setprio(1);
#pragma unroll
        for (int mi = 0; mi < 8; ++mi)
#pragma unroll
            for (int ni = 0; ni < 4; ++ni)
                acc[mi][ni] = __builtin_amdgcn_mfma_f32_16x16x32_f16(a_h[mi], b_h[ni], acc[mi][ni], 0, 0, 0);
        __builtin_amdgcn_s_setprio(0);

        if (tt < T2K - 1) WAITV8(); else WAITV0();
        __builtin_amdgcn_s_barrier();

        half8 a_l[8], b_l[4];
#pragma unroll
        for (int i = 0; i < 8; ++i) a_l[i] = frag(&slots[s1][0][0], wr * 128 + i * 16 + fr, kslot);
#pragma unroll
        for (int i = 0; i < 4; ++i) b_l[i] = frag(&slots[s1][1][0], wc * 64 + i * 16 + fr, kslot);

        if (tt < T2K - 2) {
            const int k0 = (tt + 2) * 32, sl = (2 * tt + 4) & 3;
            stage256(A_h, &slots[sl][0][0], t, row0, 1216, k0);
            stage256(B_h, &slots[sl][1][0], t, col0, 1216, k0);
        }
        __builtin_amdgcn_s_barrier();
        WAITL0();
        __builtin_amdgcn_s_setprio(1);
#pragma unroll
        for (int mi = 0; mi < 8; ++mi)
#pragma unroll
            for (int ni = 0; ni < 4; ++ni) {
                acc[mi][ni] = __builtin_amdgcn_mfma_f32_16x16x32_f16(a_h[mi], b_l[ni], acc[mi][ni], 0, 0, 0);
                acc[mi][ni] = __builtin_amdgcn_mfma_f32_16x16x32_f16(a_l[mi], b_h[ni], acc[mi][ni], 0, 0, 0);
            }
        __builtin_amdgcn_s_setprio(0);
    }

    const int r4 = (lane >> 4) * 4;
    float* C = Cf + bz * (1024L * 2048);
#pragma unroll
    for (int mi = 0; mi < 8; ++mi)
#pragma unroll
        for (int ni = 0; ni < 4; ++ni) {
            const long colg = col0 + wc * 64 + ni * 16 + fr;
#pragma unroll
            for (int r = 0; r < 4; ++r) {
                const long rowg = row0 + wr * 128 + mi * 16 + r4 + r;
                C[rowg * 2048 + colg] = acc[mi][ni][r];
            }
        }
}

// ======================= GEMM1/GEMM3: 128x128 2-phase double-buffer (R6-proven) + XCD swizzle =======================
// MODE 0 (GEMM1, no batch): XCD k owns M-stripe by in [8k,8k+8), all NBX col-blocks.
//   bid&7 -> xcd; j=bid>>3; by = xcd*8 + j/NBX; bx = j%NBX.
// MODE 1 (GEMM3, batched):  XCD k owns batch k. bz = bid&7; j=bid>>3; by=j/NBX; bx=j%NBX.
template<bool SPLIT, bool OUT16, int NBX, int MODE>
__global__ __launch_bounds__(256) void gemm16(
    const _Float16* __restrict__ Ah, const _Float16* __restrict__ Al,
    const _Float16* __restrict__ Bh, const _Float16* __restrict__ Bl,
    float* __restrict__ Cf, _Float16* __restrict__ Ch, _Float16* __restrict__ Cl,
    int N, int K, int lda, int ldb, int ldc,
    long sA, long sB, long sC)
{
    const int t = threadIdx.x;
    const int bid = blockIdx.x;
    int bx, by, bz;
    if (MODE == 0) {
        const int xcd = bid & 7, j = bid >> 3;
        by = xcd * 8 + j / NBX; bx = j % NBX; bz = 0;
    } else {
        bz = bid & 7;
        const int j = bid >> 3;
        by = j / NBX; bx = j % NBX;
    }

    const _Float16* A_h = Ah + bz * sA;
    const _Float16* B_h = Bh + bz * sB;
    const _Float16* A_l = SPLIT ? (Al + bz * sA) : nullptr;
    const _Float16* B_l = SPLIT ? (Bl + bz * sB) : nullptr;

    __shared__ __align__(16) _Float16 sAh[2][128 * 32];
    __shared__ __align__(16) _Float16 sBh[2][128 * 32];
    __shared__ __align__(16) _Float16 sAl[SPLIT ? 2 : 1][SPLIT ? 128 * 32 : 8];
    __shared__ __align__(16) _Float16 sBl[SPLIT ? 2 : 1][SPLIT ? 128 * 32 : 8];

    const long row0 = (long)by * 128;
    const int  col0 = bx * 128;

    const int wid = t >> 6, lane = t & 63;
    const int wm = (wid >> 1) * 64, wn = (wid & 1) * 64;
    const int fr = lane & 15, kslot = lane >> 4;

    f32x4 acc[4][4];
#pragma unroll
    for (int i = 0; i < 4; ++i)
#pragma unroll
        for (int j = 0; j < 4; ++j) acc[i][j] = (f32x4){0.f, 0.f, 0.f, 0.f};

    stage_tile(A_h, sAh[0], t, row0, row0 + 127, lda, 0);
    stage_tile(B_h, sBh[0], t, col0, N - 1, ldb, 0);
    if (SPLIT) {
        stage_tile(A_l, sAl[0], t, row0, row0 + 127, lda, 0);
        stage_tile(B_l, sBl[0], t, col0, N - 1, ldb, 0);
    }
    __syncthreads();

    int cur = 0;
    for (int k0 = 0; k0 < K; k0 += 32) {
        if (k0 + 32 < K) {
            const int nxt = cur ^ 1, kn = k0 + 32;
            stage_tile(A_h, sAh[nxt], t, row0, row0 + 127, lda, kn);
            stage_tile(B_h, sBh[nxt], t, col0, N - 1, ldb, kn);
            if (SPLIT) {
                stage_tile(A_l, sAl[nxt], t, row0, row0 + 127, lda, kn);
                stage_tile(B_l, sBl[nxt], t, col0, N - 1, ldb, kn);
            }
        }

        half8 a_h[4], b_h[4], a_l[4], b_l[4];
#pragma unroll
        for (int i = 0; i < 4; ++i) {
            a_h[i] = frag(sAh[cur], wm + i * 16 + fr, kslot);
            b_h[i] = frag(sBh[cur], wn + i * 16 + fr, kslot);
            if (SPLIT) {
                a_l[i] = frag(sAl[cur], wm + i * 16 + fr, kslot);
                b_l[i] = frag(sBl[cur], wn + i * 16 + fr, kslot);
            }
        }
#pragma unroll
        for (int mi = 0; mi < 4; ++mi)
#pragma unroll
            for (int ni = 0; ni < 4; ++ni) {
                acc[mi][ni] = __builtin_amdgcn_mfma_f32_16x16x32_f16(a_h[mi], b_h[ni], acc[mi][ni], 0, 0, 0);
                if (SPLIT) {
                    acc[mi][ni] = __builtin_amdgcn_mfma_f32_16x16x32_f16(a_h[mi], b_l[ni], acc[mi][ni], 0, 0, 0);
                    acc[mi][ni] = __builtin_amdgcn_mfma_f32_16x16x32_f16(a_l[mi], b_h[ni], acc[mi][ni], 0, 0, 0);
                }
            }

        __syncthreads();
        cur ^= 1;
    }

    const int r4 = (lane >> 4) * 4;
    float* C_f = OUT16 ? nullptr : (Cf + bz * sC);
#pragma unroll
    for (int mi = 0; mi < 4; ++mi)
#pragma unroll
        for (int ni = 0; ni < 4; ++ni) {
            const int colg = col0 + wn + ni * 16 + fr;
#pragma unroll
            for (int r = 0; r < 4; ++r) {
                const long rowg = row0 + wm + mi * 16 + r4 + r;
                const float v = acc[mi][ni][r];
                if (OUT16) {
                    if (colg < ldc) {
                        const float vv = (colg < N) ? v : 0.f;
                        const _Float16 hi = (_Float16)vv;
                        const _Float16 lo = (_Float16)(vv - (float)hi);
                        Ch[rowg * ldc + colg] = hi;
                        Cl[rowg * ldc + colg] = lo;
                    }
                } else {
                    if (colg < N) C_f[rowg * (long)ldc + colg] = v;
                }
            }
        }
}

// fused fp32 -> (hi,lo) f16 split for query_in and W
__global__ __launch_bounds__(256) void qw_cvt(
    const float* __restrict__ Q, _Float16* __restrict__ QH, _Float16* __restrict__ QL,
    const float* __restrict__ Wt, _Float16* __restrict__ WH, _Float16* __restrict__ WL)
{
    const long NQ = 8192L * 1024 / 4;
    const long NT = NQ + 1200L * 1024 / 4;
    for (long i = (long)blockIdx.x * 256 + threadIdx.x; i < NT; i += (long)gridDim.x * 256) {
        const float* src; _Float16 *dh, *dl; long j;
        if (i < NQ) { j = i; src = Q; dh = QH; dl = QL; }
        else        { j = i - NQ; src = Wt; dh = WH; dl = WL; }
        float4 v = *(const float4*)(src + j * 4);
        const _Float16 h0 = (_Float16)v.x, h1 = (_Float16)v.y, h2 = (_Float16)v.z, h3 = (_Float16)v.w;
        const _Float16 l0 = (_Float16)(v.x - (float)h0), l1 = (_Float16)(v.y - (float)h1);
        const _Float16 l2 = (_Float16)(v.z - (float)h2), l3 = (_Float16)(v.w - (float)h3);
        *(half4v*)(dh + j * 4) = (half4v){h0, h1, h2, h3};
        *(half4v*)(dl + j * 4) = (half4v){l0, l1, l2, l3};
    }
}

// fused ctx prep: one read of ctx f32 -> hi/lo split [8][2048][1216] + f16 transpose [8][1200][2048]
__global__ __launch_bounds__(256) void ctx_prep(const float* __restrict__ X,
    _Float16* __restrict__ H, _Float16* __restrict__ L, _Float16* __restrict__ T)
{
    const int b = blockIdx.z;
    const float* Xb = X + (long)b * 2048 * 1200;
    _Float16* Hb = H + (long)b * 2048 * 1216;
    _Float16* Lb = L + (long)b * 2048 * 1216;
    _Float16* Tb = T + (long)b * 1200 * 2048;
    __shared__ _Float16 tl[32][33];
    const int tx = threadIdx.x & 31, ty = threadIdx.x >> 5;
    const int s0 = blockIdx.x * 32, q0 = blockIdx.y * 32;
#pragma unroll
    for (int p = 0; p < 4; ++p) {
        const int q = q0 + ty + p * 8, s = s0 + tx;
        const float v = (s < 1200) ? Xb[(long)q * 1200 + s] : 0.f;
        const _Float16 hi = (_Float16)v;
        Hb[(long)q * 1216 + s] = hi;
        Lb[(long)q * 1216 + s] = (_Float16)(v - (float)hi);
        tl[tx][ty + p * 8] = hi;
    }
    __syncthreads();
#pragma unroll
    for (int p = 0; p < 4; ++p) {
        const int s = s0 + ty + p * 8;
        if (s < 1200) Tb[(long)s * 2048 + q0 + tx] = tl[ty + p * 8][tx];
    }
}

// in-place row softmax (2048) + f16 copy for GEMM3
__global__ __launch_bounds__(256) void softmax_k(float* __restrict__ w, _Float16* __restrict__ w16)
{
    float* p = w + (long)blockIdx.x * 2048;
    half4v* p16 = (half4v*)(w16 + (long)blockIdx.x * 2048);
    const int t = threadIdx.x;
    float4 v0 = ((const float4*)p)[t];
    float4 v1 = ((const float4*)p)[t + 256];

    float m = fmaxf(fmaxf(fmaxf(v0.x, v0.y), fmaxf(v0.z, v0.w)),
                    fmaxf(fmaxf(v1.x, v1.y), fmaxf(v1.z, v1.w)));
#pragma unroll
    for (int off = 1; off < 64; off <<= 1) m = fmaxf(m, __shfl_xor(m, off));
    __shared__ float redm[4], reds[4];
    const int wave = t >> 6, lane = t & 63;
    if (lane == 0) redm[wave] = m;
    __syncthreads();
    m = fmaxf(fmaxf(redm[0], redm[1]), fmaxf(redm[2], redm[3]));

    float e[8];
    e[0] = __expf(v0.x - m); e[1] = __expf(v0.y - m);
    e[2] = __expf(v0.z - m); e[3] = __expf(v0.w - m);
    e[4] = __expf(v1.x - m); e[5] = __expf(v1.y - m);
    e[6] = __expf(v1.z - m); e[7] = __expf(v1.w - m);

    float s = ((e[0] + e[1]) + (e[2] + e[3])) + ((e[4] + e[5]) + (e[6] + e[7]));
#pragma unroll
    for (int off = 1; off < 64; off <<= 1) s += __shfl_xor(s, off);
    if (lane == 0) reds[wave] = s;
    __syncthreads();
    s = (reds[0] + reds[1]) + (reds[2] + reds[3]);

    const float inv = 1.0f / s;
    float o0 = e[0] * inv, o1 = e[1] * inv, o2 = e[2] * inv, o3 = e[3] * inv;
    float o4 = e[4] * inv, o5 = e[5] * inv, o6 = e[6] * inv, o7 = e[7] * inv;
    ((float4*)p)[t]       = make_float4(o0, o1, o2, o3);
    ((float4*)p)[t + 256] = make_float4(o4, o5, o6, o7);
    p16[t]       = (half4v){(_Float16)o0, (_Float16)o1, (_Float16)o2, (_Float16)o3};
    p16[t + 256] = (half4v){(_Float16)o4, (_Float16)o5, (_Float16)o6, (_Float16)o7};
}

extern "C" void kernel_launch(void* const* d_in, const int* in_sizes, int n_in,
                              void* d_out, int out_size, void* d_ws, size_t ws_size,
                              hipStream_t stream)
{
    const float* query_in = (const float*)d_in[0]; // [8,1024,1024]
    const float* context  = (const float*)d_in[1]; // [8,2048,1200]
    const float* W        = (const float*)d_in[2]; // [1200,1024]

    float* mix    = (float*)d_out;                 // [8,1024,1200]
    float* scores = (float*)d_out + 9830400LL;     // [8,1024,2048] -> softmax in place

    // ws layout (halfs); ~220 MB
    _Float16* qh  = (_Float16*)d_ws;               // query_in hi  [8192,1024]
    _Float16* ql  = qh  + 8388608;                 // query_in lo
    _Float16* wh  = ql  + 8388608;                 // W hi         [1200,1024]
    _Float16* wl  = wh  + 1228800;                 // W lo
    _Float16* ch  = wl  + 1228800;                 // ctx hi       [16384,1216] (zero-pad 1200..1215)
    _Float16* cl  = ch  + 19922944;                // ctx lo
    _Float16* ct  = cl  + 19922944;                // ctxT f16     [8][1200][2048]
    _Float16* qeh = ct  + 19660800;                // query hi     [8192,1216]
    _Float16* qel = qeh + 9961472;                 // query lo
    _Float16* w16 = qel + 9961472;                 // weights f16  [8192,2048]

    dim3 blk(256);

    qw_cvt<<<2400, blk, 0, stream>>>(query_in, qh, ql, W, wh, wl);
    ctx_prep<<<dim3(38, 64, 8), blk, 0, stream>>>(context, ch, cl, ct);

    // GEMM1: query(hi/lo)[8192,1216] = qin[8192,1024] @ W[1200,1024]^T
    // flat grid 640, MODE0 swizzle: XCD k owns by in [8k,8k+8) x bx in [0,10)
    gemm16<true, true, 10, 0><<<dim3(640), blk, 0, stream>>>(
        qh, ql, wh, wl, nullptr, qeh, qel,
        1200, 1024, 1024, 1024, 1216, 0, 0, 0);

    // GEMM2: scores[b][1024,2048] = qe_b[1024,1216] @ ctx_b[2048,1216]^T
    // flat grid 256, batch pinned to XCD
    gemm2_8p<<<dim3(256), dim3(512), 0, stream>>>(qeh, qel, ch, cl, scores);

    softmax_k<<<dim3(8192), blk, 0, stream>>>(scores, w16);

    // GEMM3: mix[b][1024,1200] = w16_b[1024,2048] @ ctxT_b[1200,2048]^T
    // flat grid 640, MODE1 swizzle: batch pinned to XCD
    gemm16<false, false, 10, 1><<<dim3(640), blk, 0, stream>>>(
        w16, nullptr, ct, nullptr, mix, nullptr, nullptr,
        1200, 2048, 2048, 2048, 1200, 1024L * 2048, 1200L * 2048, 1024L * 1200);
}